// Round 4
// baseline (159.288 us; speedup 1.0000x reference)
//
#include <hip/hip_runtime.h>
#include <stdint.h>

#define NB 4
#define NN 8192
#define NE 2048
#define NC 64
#define KS2 8          // n-split for k_edge2 (1024 n per block)

typedef __bf16 bf16x8 __attribute__((ext_vector_type(8)));
typedef float f32x16 __attribute__((ext_vector_type(16)));
typedef unsigned long long u64;

__device__ __forceinline__ unsigned short f2bf(float f) {
  union { float f; uint32_t u; } v; v.f = f;
  return (unsigned short)((v.u + 0x7FFFu + ((v.u >> 16) & 1u)) >> 16);
}
__device__ __forceinline__ bf16x8 ld_bf8(const void* p) { return *(const bf16x8*)p; }

// byte (8 H-bits) -> bf16x8 of 0.0/1.0
__device__ __forceinline__ bf16x8 expand8(uint32_t byte) {
  union { uint32_t u[4]; bf16x8 v; } r;
  #pragma unroll
  for (int p = 0; p < 4; ++p) {
    const uint32_t t = (byte >> (2 * p)) & 3u;
    r.u[p] = (t & 1u) * 0x3F80u + (t & 2u) * 0x1FC00000u;
  }
  return r.v;
}

// in-register 64x64 bit-matrix transpose across the wave (lane=row, u64=cols)
__device__ __forceinline__ u64 bt_step(u64 x, int k, u64 M1, int lane) {
  const u64 y = (u64)__shfl_xor((long long)x, k, 64);
  const u64 M0 = ~M1;
  return ((lane & k) == 0) ? ((x & M0) | ((y & M0) << k))
                           : ((x & M1) | ((y >> k) & M0));
}
__device__ __forceinline__ u64 bit_transpose64(u64 x, int lane) {
  x = bt_step(x, 1,  0xAAAAAAAAAAAAAAAAull, lane);
  x = bt_step(x, 2,  0xCCCCCCCCCCCCCCCCull, lane);
  x = bt_step(x, 4,  0xF0F0F0F0F0F0F0F0ull, lane);
  x = bt_step(x, 8,  0xFF00FF00FF00FF00ull, lane);
  x = bt_step(x, 16, 0xFFFF0000FFFF0000ull, lane);
  x = bt_step(x, 32, 0xFFFFFFFF00000000ull, lane);
  return x;
}

// ---------------------------------------------------------------------------
// K1: x' = x @ theta (fp32), stored TRANSPOSED bf16: xt[b][o][n].
// ---------------------------------------------------------------------------
__global__ __launch_bounds__(256) void k_transform(
    const float* __restrict__ x, const float* __restrict__ theta,
    unsigned short* __restrict__ xt) {
  const int b = blockIdx.y, n0 = blockIdx.x * 64;
  __shared__ float xs[64][65];
  __shared__ float th[64][64];
  const int tid = threadIdx.x;
  for (int k = tid; k < 4096; k += 256) th[k >> 6][k & 63] = theta[k];
  const float* xrow = x + ((size_t)b * NN + n0) * NC;
  for (int k = tid; k < 4096; k += 256) xs[k >> 6][k & 63] = xrow[k];
  __syncthreads();
  const int w = tid >> 6, l = tid & 63;
  float acc[16];
  #pragma unroll
  for (int j = 0; j < 16; ++j) acc[j] = 0.f;
  #pragma unroll 4
  for (int i = 0; i < 64; ++i) {
    const float xv = xs[l][i];
    const float4* t4 = (const float4*)(&th[i][w * 16]);
    const float4 a0 = t4[0], a1 = t4[1], a2 = t4[2], a3 = t4[3];
    acc[0]  += xv * a0.x; acc[1]  += xv * a0.y; acc[2]  += xv * a0.z; acc[3]  += xv * a0.w;
    acc[4]  += xv * a1.x; acc[5]  += xv * a1.y; acc[6]  += xv * a1.z; acc[7]  += xv * a1.w;
    acc[8]  += xv * a2.x; acc[9]  += xv * a2.y; acc[10] += xv * a2.z; acc[11] += xv * a2.w;
    acc[12] += xv * a3.x; acc[13] += xv * a3.y; acc[14] += xv * a3.z; acc[15] += xv * a3.w;
  }
  #pragma unroll
  for (int j = 0; j < 16; ++j)
    xt[((size_t)b * NC + (w * 16 + j)) * NN + n0 + l] = f2bf(acc[j]);
}

// ---------------------------------------------------------------------------
// K_pack: streams H ONCE, row-sequential 1KB/instr (memcpy-class pattern).
// Block (b, 64-n strip, e-half); wave w owns e-strip of 256 (lane: 4 e's).
// Per row: 1 float4 load; per-lane shift-register builds bitsN words (bit r =
// row r). Butterfly transpose yields bitsE words (lane=node, bits=64 e's in
// PERMUTED order: e' = ew*64+bit <-> e_nat = (ew>>2)*256 + 4*bit + (ew&3)).
// The permutation is carried consistently through xe/deg/k_node (cancels).
// ---------------------------------------------------------------------------
__global__ __launch_bounds__(256) void k_pack(
    const float* __restrict__ H, u64* __restrict__ bitsN,
    u64* __restrict__ bitsE) {
  const int ns = blockIdx.x, b = blockIdx.y, eh = blockIdx.z;
  const int n0 = ns * 64;
  const int w = threadIdx.x >> 6, l = threadIdx.x & 63;
  const int strip = eh * 4 + w;            // e-strip of 256 floats
  const int ebase = strip * 256 + 4 * l;   // lane's float4 position
  const float* Hb = H + ((size_t)b * NN + n0) * NE + ebase;

  u64 wn0 = 0, wn1 = 0, wn2 = 0, wn3 = 0;
  float4 pf[8];
  #pragma unroll
  for (int j = 0; j < 8; ++j) pf[j] = *(const float4*)(Hb + (size_t)j * NE);

  #pragma unroll 8
  for (int r = 0; r < 64; ++r) {
    const float4 v = pf[r & 7];
    if (r + 8 < 64) pf[r & 7] = *(const float4*)(Hb + (size_t)(r + 8) * NE);
    wn0 = (wn0 >> 1) | ((v.x != 0.f) ? 0x8000000000000000ull : 0ull);
    wn1 = (wn1 >> 1) | ((v.y != 0.f) ? 0x8000000000000000ull : 0ull);
    wn2 = (wn2 >> 1) | ((v.z != 0.f) ? 0x8000000000000000ull : 0ull);
    wn3 = (wn3 >> 1) | ((v.w != 0.f) ? 0x8000000000000000ull : 0ull);
  }
  // bitsN[b][ns][e_nat]: 4 consecutive u64 per lane -> 2KB contiguous / wave
  u64* bn = bitsN + ((size_t)b * 128 + ns) * NE + ebase;
  bn[0] = wn0; bn[1] = wn1; bn[2] = wn2; bn[3] = wn3;
  // bitsE[b][ew][n]: transpose -> lane l holds word for node n0+l
  u64* be = bitsE + (size_t)b * 32 * NN + n0 + l;
  be[(size_t)(strip * 4 + 0) * NN] = bit_transpose64(wn0, l);
  be[(size_t)(strip * 4 + 1) * NN] = bit_transpose64(wn1, l);
  be[(size_t)(strip * 4 + 2) * NN] = bit_transpose64(wn2, l);
  be[(size_t)(strip * 4 + 3) * NN] = bit_transpose64(wn3, l);
}

// ---------------------------------------------------------------------------
// K_edge2: C[o 64][e' 64] = sum_n xt[o][n] * H[n][e'].  A = xt (L2-resident,
// contiguous 16B frags), B = bitsN bytes expanded in-register. No LDS, no
// barriers. deg_e by popcount (free). ks splits n into 8x1024.
// ---------------------------------------------------------------------------
__global__ __launch_bounds__(256) void k_edge2(
    const u64* __restrict__ bitsN, const unsigned short* __restrict__ xt,
    float* __restrict__ xe_part, float* __restrict__ deg_part) {
  const int ew = blockIdx.x, b = blockIdx.y, ks = blockIdx.z;
  const int tid = threadIdx.x, w = tid >> 6, l = tid & 63, q = l >> 5;
  const int orow = (w & 1) * 32 + (l & 31);
  const int icol = (w >> 1) * 32 + (l & 31);
  const int enat = (ew >> 2) * 256 + 4 * icol + (ew & 3);   // permuted->natural

  const unsigned short* Ab = xt + ((size_t)b * NC + orow) * NN + ks * 1024;
  const u64* Nb = bitsN + ((size_t)b * 128 + ks * 16) * NE + enat;

  f32x16 acc;
  #pragma unroll
  for (int j = 0; j < 16; ++j) acc[j] = 0.f;
  int dcount = 0;

  for (int nt = 0; nt < 16; ++nt) {
    const u64 wbits = Nb[(size_t)nt * NE];
    dcount += __popcll(wbits);
    #pragma unroll
    for (int kk = 0; kk < 4; ++kk) {
      const bf16x8 av = ld_bf8(Ab + nt * 64 + kk * 16 + q * 8);
      const bf16x8 bv = expand8((uint32_t)(wbits >> (8 * (kk * 2 + q))) & 0xFFu);
      acc = __builtin_amdgcn_mfma_f32_32x32x16_bf16(av, bv, acc, 0, 0, 0);
    }
  }
  float* xo = xe_part + ((size_t)ks * NB + b) * (NC * NE);
  #pragma unroll
  for (int r = 0; r < 16; ++r) {
    const int ro = (w & 1) * 32 + 4 * q + (r & 3) + 8 * (r >> 2);
    xo[(size_t)ro * NE + ew * 64 + icol] = acc[r];
  }
  if ((w & 1) == 0 && q == 0)
    deg_part[((size_t)ks * NB + b) * NE + ew * 64 + icol] = (float)dcount;
}

// ---------------------------------------------------------------------------
// K_deg: deg_inv[b][e'] = 1 / sum_ks deg_part.
// ---------------------------------------------------------------------------
__global__ __launch_bounds__(256) void k_deg(
    const float* __restrict__ deg_part, float* __restrict__ deg_inv) {
  const int idx = blockIdx.x * 256 + threadIdx.x;   // < NB*NE
  float s = 0.f;
  #pragma unroll
  for (int ks = 0; ks < KS2; ++ks) s += deg_part[(size_t)ks * (NB * NE) + idx];
  deg_inv[idx] = s > 0.f ? 1.0f / s : 0.f;
}

// ---------------------------------------------------------------------------
// K_edge_norm: xe_b[b][o][e'] = bf16(sum_ks xe_part * deg_inv).
// ---------------------------------------------------------------------------
__global__ __launch_bounds__(256) void k_edge_norm(
    const float* __restrict__ xe_part, const float* __restrict__ deg_inv,
    unsigned short* __restrict__ xe_b) {
  const int idx = blockIdx.x * 256 + threadIdx.x;   // < NB*NC*NE (b,o,e')
  const int e = idx & (NE - 1);
  const int b = idx >> 17;
  float s = 0.f;
  #pragma unroll
  for (int ks = 0; ks < KS2; ++ks) s += xe_part[(size_t)ks * (NB * NC * NE) + idx];
  xe_b[idx] = f2bf(s * deg_inv[b * NE + e]);
}

// ---------------------------------------------------------------------------
// K_node2: C[n 64][o 64] = sum_e' H[n][e'] * xe[e'][o]; A = bitsE bytes
// (register expand), B = xe_b[o][e'] contiguous frags. deg_n = popcount.
// ---------------------------------------------------------------------------
__global__ __launch_bounds__(256) void k_node2(
    const u64* __restrict__ bitsE, const unsigned short* __restrict__ xe_b,
    const float* __restrict__ bias, float* __restrict__ out) {
  const int ns = blockIdx.x, b = blockIdx.y;
  const int n0 = ns * 64;
  const int tid = threadIdx.x, w = tid >> 6, l = tid & 63, q = l >> 5;
  const int arow = (w >> 1) * 32 + (l & 31);   // n-row
  const int ocol = (w & 1) * 32 + (l & 31);    // o-col
  __shared__ float ldsDeg[64];

  const u64* Eb = bitsE + (size_t)b * 32 * NN + n0 + arow;
  const unsigned short* Bb = xe_b + ((size_t)b * NC + ocol) * NE;

  f32x16 acc;
  #pragma unroll
  for (int j = 0; j < 16; ++j) acc[j] = 0.f;
  int dcount = 0;

  for (int et = 0; et < 32; ++et) {
    const u64 wbits = Eb[(size_t)et * NN];
    dcount += __popcll(wbits);
    #pragma unroll
    for (int kk = 0; kk < 4; ++kk) {
      const bf16x8 av = expand8((uint32_t)(wbits >> (8 * (kk * 2 + q))) & 0xFFu);
      const bf16x8 bv = ld_bf8(Bb + et * 64 + kk * 16 + q * 8);
      acc = __builtin_amdgcn_mfma_f32_32x32x16_bf16(av, bv, acc, 0, 0, 0);
    }
  }
  if ((w & 1) == 0 && q == 0)
    ldsDeg[arow] = dcount > 0 ? 1.0f / (float)dcount : 0.f;
  __syncthreads();
  const float bv0 = bias[ocol];
  #pragma unroll
  for (int r = 0; r < 16; ++r) {
    const int row = (w >> 1) * 32 + 4 * q + (r & 3) + 8 * (r >> 2);
    out[((size_t)b * NN + n0 + row) * NC + ocol] = acc[r] * ldsDeg[row] + bv0;
  }
}

// ---------------------------------------------------------------------------
// ws: xt @0 (4MB) | bitsN @4MB (8MB) | bitsE @12MB (8MB) | xe_part @20MB
// (16MB) | deg_part @36MB (256KB) | deg_inv (32KB) | xe_b @37MB (1MB).
// All buffers fully rewritten each call -> no memset, deterministic.
// ---------------------------------------------------------------------------
extern "C" void kernel_launch(void* const* d_in, const int* in_sizes, int n_in,
                              void* d_out, int out_size, void* d_ws, size_t ws_size,
                              hipStream_t stream) {
  const float* x     = (const float*)d_in[0];
  const float* H     = (const float*)d_in[1];
  const float* theta = (const float*)d_in[2];
  const float* bias  = (const float*)d_in[3];
  float* out = (float*)d_out;
  char* ws = (char*)d_ws;

  unsigned short* xt   = (unsigned short*)ws;
  u64* bitsN           = (u64*)(ws + (4ull << 20));
  u64* bitsE           = (u64*)(ws + (12ull << 20));
  float* xe_part       = (float*)(ws + (20ull << 20));
  float* deg_part      = (float*)(ws + (36ull << 20));
  float* deg_inv       = (float*)(ws + (36ull << 20) + (256ull << 10));
  unsigned short* xe_b = (unsigned short*)(ws + (37ull << 20));

  k_transform<<<dim3(NN / 64, NB), 256, 0, stream>>>(x, theta, xt);
  k_pack<<<dim3(NN / 64, NB, 2), 256, 0, stream>>>(H, bitsN, bitsE);
  k_edge2<<<dim3(32, NB, KS2), 256, 0, stream>>>(bitsN, xt, xe_part, deg_part);
  k_deg<<<dim3((NB * NE) / 256), 256, 0, stream>>>(deg_part, deg_inv);
  k_edge_norm<<<dim3((NB * NC * NE) / 256), 256, 0, stream>>>(xe_part, deg_inv, xe_b);
  k_node2<<<dim3(NN / 64, NB), 256, 0, stream>>>(bitsE, xe_b, bias, out);
}